// Round 8
// baseline (493.963 us; speedup 1.0000x reference)
//
#include <hip/hip_runtime.h>
#include <hip/hip_cooperative_groups.h>
#include <math.h>

namespace cg = cooperative_groups;

#define NCLS 16
#define NPIX 16384
#define CHN 256
#define MAXV 200
#define SORTN 2048
#define NBLK 512
#define NTHR 256

typedef unsigned long long ull;

// ---------------- ws layout (bytes) ----------------
// 0       : double acc                 (zeroed by block 0 pre-sync)
// 8       : int ticket
// 64      : int gcnt[128]
// 1024    : float pos_sum[2048]
// 16384   : int counts_part[512*16]    (per-block histograms, non-atomic)
// 65536   : ull thrKey[128]
// 1048576 : ull keybuf[128*2048]       (2 MB)

__global__ __launch_bounds__(NTHR, 2) void k_fused(
    const float* __restrict__ feats,
    const int* __restrict__ predict,
    int* __restrict__ counts_part,
    ull* __restrict__ keybuf,
    ull* __restrict__ thrKey,
    int* __restrict__ gcnt,
    float* __restrict__ pos_sum,
    double* __restrict__ acc,
    int* __restrict__ ticket,
    float* __restrict__ out)
{
    cg::grid_group grid = cg::this_grid();
    __shared__ int pmap_l[128];
    __shared__ int pcls_l[128];
    __shared__ int Lp_l[128];
    __shared__ int chan_l[16];
    __shared__ int sP, sD, skv;
    __shared__ union {
        int h[NCLS];
        struct { int c[128]; int sc[128]; int mn[128]; int present[NCLS]; } b;
        struct { int lcount[NCLS]; int gbase[NCLS]; } c;
        struct { ull keys[SORTN]; int whist[4][256]; int scan[257]; int wtot[4];
                 ull sprefix; int sremain; int sdone; } d;
        float gacc[NCLS * 16];
        struct { float ppd[128 * 16]; float nr[128]; double red[NTHR]; } f;
    } su;

    const int tid  = threadIdx.x;
    const int bid  = blockIdx.x;
    const int lane = tid & 63;
    const int wv   = tid >> 6;
    const int t    = bid * NTHR + tid;       // global pixel id = b*NPIX + pix
    const int b    = t >> 14;                // 64 blocks per image, block-uniform
    const int pix  = t & (NPIX - 1);

    // ---- block 0: zero small global accumulators (first used after sync1+) ----
    if (bid == 0) {
        for (int i = tid; i < 2048; i += NTHR) pos_sum[i] = 0.f;
        if (tid < 128) gcnt[tid] = 0;
        if (tid == 0) { *acc = 0.0; *ticket = 0; }
    }

    // ---- Phase A: per-pixel top-2 over 256 channels + per-block histogram ----
    if (tid < NCLS) su.h[tid] = 0;
    __syncthreads();
    const int v = predict[t];
    if (v >= 0 && v < NCLS) atomicAdd(&su.h[v], 1);

    const float* fp = feats + ((size_t)b * CHN << 14) + pix;
    float x16[16];                           // channels 0..15 stashed for E/F
    float m1 = -INFINITY, m2 = -INFINITY;
    for (int cb = 0; cb < CHN; cb += 8) {
        float xs[8];
#pragma unroll
        for (int u = 0; u < 8; ++u) xs[u] = fp[(size_t)(cb + u) << 14];
        if (cb == 0) {
#pragma unroll
            for (int u = 0; u < 8; ++u) x16[u] = xs[u];
        } else if (cb == 8) {
#pragma unroll
            for (int u = 0; u < 8; ++u) x16[8 + u] = xs[u];
        }
#pragma unroll
        for (int u = 0; u < 8; ++u) {
            float val = xs[u];
            if (val > m1) { m2 = m1; m1 = val; }
            else if (val > m2) m2 = val;
        }
    }
    const float ct = m1 - m2;                // certainty, stays in register
    __syncthreads();
    if (tid < NCLS) counts_part[bid * NCLS + tid] = su.h[tid];

    grid.sync();   // counts_part + zeroed accumulators visible

    // ---- Phase B: plan, recomputed redundantly per block (LDS-local) ----
    if (tid < NCLS) su.b.present[tid] = 0;
    if (tid < 128) {
        int bb = tid >> 4, vv = tid & 15, s = 0;
        for (int j = 0; j < 64; ++j) s += counts_part[((bb << 6) + j) * NCLS + vv];
        su.b.c[tid] = s;
    }
    __syncthreads();
    int e = 0;
    if (tid < 128) {
        if (su.b.c[tid] > 0) atomicOr(&su.b.present[tid & 15], 1);
        e = (su.b.c[tid] >= MAXV) ? 1 : 0;
        su.b.sc[tid] = e;
        su.b.mn[tid] = e ? su.b.c[tid] : 0x7fffffff;
    }
    __syncthreads();
    for (int off = 1; off < 128; off <<= 1) {
        int add = 0;
        if (tid < 128 && tid >= off) add = su.b.sc[tid - off];
        __syncthreads();
        if (tid < 128) su.b.sc[tid] += add;
        __syncthreads();
    }
    for (int s2 = 64; s2 > 0; s2 >>= 1) {
        if (tid < s2) su.b.mn[tid] = min(su.b.mn[tid], su.b.mn[tid + s2]);
        __syncthreads();
    }
    if (tid < 128) {
        pmap_l[tid] = e ? (su.b.sc[tid] - 1) : -1;
        if (e) {
            int p2 = su.b.sc[tid] - 1;
            pcls_l[p2] = tid & 15;
            Lp_l[p2]   = su.b.c[tid];
        }
    }
    if (tid == 0) {
        int D = 0;
        for (int vv = 0; vv < NCLS; ++vv) if (su.b.present[vv]) chan_l[D++] = vv;
        sP  = su.b.sc[127];
        sD  = D;
        skv = su.b.mn[0] / 2;                // k = n_view // 2
    }
    __syncthreads();

    // ---- Phase C: block-aggregated key scatter into keybuf ----
    const int p = (v >= 0 && v < NCLS) ? pmap_l[(b << 4) + v] : -1;
    if (tid < NCLS) su.c.lcount[tid] = 0;
    __syncthreads();
    int lpos = 0;
    if (p >= 0) lpos = atomicAdd(&su.c.lcount[v], 1);
    __syncthreads();
    if (tid < NCLS) {
        int cc = su.c.lcount[tid];
        int pp = pmap_l[(b << 4) + tid];
        su.c.gbase[tid] = (pp >= 0 && cc > 0) ? atomicAdd(&gcnt[pp], cc) : 0;
    }
    __syncthreads();
    ull mykey = 0;
    if (p >= 0) {
        unsigned int mm = __float_as_uint(ct) | 0x80000000u;   // cert >= 0 monotonic map
        mykey = ((ull)mm << 32) | (ull)(0xFFFFFFFFu - (unsigned)pix);
        int pos = su.c.gbase[v] + lpos;
        if (pos < SORTN) keybuf[((size_t)p << 11) + pos] = mykey;
    }

    grid.sync();   // keybuf + gcnt visible

    // ---- Phase D: radix-select kv-th largest key per group (blocks 0..P-1) ----
    if (bid < sP) {
        const int p2 = bid;
        int L = gcnt[p2]; if (L > SORTN) L = SORTN;
        int kv = skv < L ? skv : L;
        if (tid == 0) { su.d.sprefix = 0; su.d.sremain = kv; su.d.sdone = 0; }
        for (int i = tid; i < L; i += NTHR) su.d.keys[i] = keybuf[((size_t)p2 << 11) + i];
        __syncthreads();
        for (int shift = 56; shift >= 0; shift -= 8) {
            if (su.d.sdone) break;                   // uniform (read post-barrier)
            for (int i = tid; i < 4 * 256; i += NTHR) ((int*)su.d.whist)[i] = 0;
            ull pref = su.d.sprefix;
            int rem  = su.d.sremain;
            __syncthreads();
            ull maskHi = (shift == 56) ? 0ULL : (~0ULL) << (shift + 8);
            for (int i = tid; i < L; i += NTHR) {
                ull kk = su.d.keys[i];
                if ((kk & maskHi) == pref)
                    atomicAdd(&su.d.whist[wv][(int)((kk >> shift) & 255)], 1);
            }
            __syncthreads();
            int s = su.d.whist[0][tid] + su.d.whist[1][tid]
                  + su.d.whist[2][tid] + su.d.whist[3][tid];
            for (int off = 1; off < 64; off <<= 1) {      // wave suffix scan
                int o = __shfl_down(s, off, 64);
                if (lane + off < 64) s += o;
            }
            if (lane == 0) su.d.wtot[wv] = s;
            __syncthreads();
            {
                int offs = 0;
                for (int w2 = wv + 1; w2 < 4; ++w2) offs += su.d.wtot[w2];
                s += offs;
                su.d.scan[tid] = s;
                if (tid == 0) su.d.scan[256] = 0;
            }
            __syncthreads();
            {
                int nxt = su.d.scan[tid + 1];
                if (s >= rem && nxt < rem) {              // crossing bin
                    su.d.sprefix = pref | ((ull)tid << shift);
                    su.d.sremain = rem - nxt;
                    if (s == rem) su.d.sdone = 1;         // low bits irrelevant
                }
            }
            __syncthreads();
        }
        if (tid == 0) thrKey[p2] = su.d.sprefix;
    }

    grid.sync();   // thrKey visible

    // ---- Phase E: selection + accumulation into pos_sum ----
    const int D = sD;
    const bool ident = (D == 16);     // classes ⊂ [0,16) sorted ⇒ chan = identity
    if (!ident && p >= 0) {
        for (int d2 = 0; d2 < D; ++d2) x16[d2] = fp[(size_t)chan_l[d2] << 14];
    }
    bool selp = false;
    if (p >= 0) selp = (mykey >= thrKey[p]);
    su.gacc[tid] = 0.f;
    __syncthreads();
    if (selp) {
        if (ident) {
#pragma unroll
            for (int d2 = 0; d2 < 16; ++d2) atomicAdd(&su.gacc[(v << 4) + d2], x16[d2]);
        } else {
            for (int d2 = 0; d2 < D; ++d2) atomicAdd(&su.gacc[(v << 4) + d2], x16[d2]);
        }
    }
    __syncthreads();
    {
        int pp = pmap_l[(b << 4) + (tid >> 4)];
        if (pp >= 0 && su.gacc[tid] != 0.f)
            atomicAdd(&pos_sum[(pp << 4) + (tid & 15)], su.gacc[tid]);
    }

    grid.sync();   // pos_sum complete

    // ---- Phase F: inter loss (all), intra pair loss (block 0), publish ----
    const int P = sP;
    for (int i = tid; i < (P << 4); i += NTHR) su.f.ppd[i] = pos_sum[i];
    __syncthreads();
    for (int pp = tid; pp < P; pp += NTHR) {
        float s = 0.f;
#pragma unroll
        for (int d2 = 0; d2 < 16; ++d2) { float y = su.f.ppd[(pp << 4) + d2]; s += y * y; }
        su.f.nr[pp] = sqrtf(s);
    }
    __syncthreads();
    double term = 0.0;
    if (p >= 0) {
        float dot = 0.f, nv2 = 0.f;
        if (ident) {
#pragma unroll
            for (int d2 = 0; d2 < 16; ++d2) {
                float y = su.f.ppd[(p << 4) + d2];
                dot += x16[d2] * y; nv2 += x16[d2] * x16[d2];
            }
        } else {
            for (int d2 = 0; d2 < D; ++d2) {
                float y = su.f.ppd[(p << 4) + d2];
                dot += x16[d2] * y; nv2 += x16[d2] * x16[d2];
            }
        }
        float den = fmaxf(sqrtf(nv2) * su.f.nr[p], 1e-8f);
        term = (1.0 - (double)(dot / den)) / ((double)Lp_l[p] * (double)P);
    }
    su.f.red[tid] = term;
    __syncthreads();
    for (int s2 = 128; s2 > 0; s2 >>= 1) {
        if (tid < s2) su.f.red[tid] += su.f.red[tid + s2];
        __syncthreads();
    }
    if (tid == 0) atomicAdd(acc, su.f.red[0]);

    if (bid == 0) {
        __syncthreads();
        double num = 0.0; int cnt = 0;
        for (int idx = tid; idx < P * P; idx += NTHR) {
            int i2 = idx / P, j2 = idx - i2 * P;
            if (pcls_l[i2] != pcls_l[j2]) {
                float dot = 0.f;
#pragma unroll
                for (int d2 = 0; d2 < 16; ++d2)
                    dot += su.f.ppd[(i2 << 4) + d2] * su.f.ppd[(j2 << 4) + d2];
                num += (double)(dot / (su.f.nr[i2] * su.f.nr[j2])) + 1.0;
                cnt++;
            }
        }
        su.f.red[tid] = num; __syncthreads();
        for (int s2 = 128; s2 > 0; s2 >>= 1) {
            if (tid < s2) su.f.red[tid] += su.f.red[tid + s2];
            __syncthreads();
        }
        double totnum = su.f.red[0]; __syncthreads();
        su.f.red[tid] = (double)cnt; __syncthreads();
        for (int s2 = 128; s2 > 0; s2 >>= 1) {
            if (tid < s2) su.f.red[tid] += su.f.red[tid + s2];
            __syncthreads();
        }
        if (tid == 0) atomicAdd(acc, totnum / su.f.red[0]);
    }
    __syncthreads();
    __threadfence();
    if (tid == 0) {
        int done = atomicAdd(ticket, 1);
        if (done == (int)gridDim.x - 1)
            out[0] = (float)atomicAdd(acc, 0.0);   // coherent read of final sum
    }
}

extern "C" void kernel_launch(void* const* d_in, const int* in_sizes, int n_in,
                              void* d_out, int out_size, void* d_ws, size_t ws_size,
                              hipStream_t stream) {
    (void)in_sizes; (void)n_in; (void)out_size; (void)ws_size;
    const float* feats = (const float*)d_in[0];
    const int* predict = (const int*)d_in[2];   // labels (d_in[1]) unused
    char* ws = (char*)d_ws;
    double* acc      = (double*)ws;
    int* ticket      = (int*)(ws + 8);
    int* gcnt        = (int*)(ws + 64);
    float* pos_sum   = (float*)(ws + 1024);
    int* counts_part = (int*)(ws + 16384);
    ull* thrKey      = (ull*)(ws + 65536);
    ull* keybuf      = (ull*)(ws + 1048576);
    float* out       = (float*)d_out;

    void* kargs[] = {
        (void*)&feats, (void*)&predict, (void*)&counts_part, (void*)&keybuf,
        (void*)&thrKey, (void*)&gcnt, (void*)&pos_sum, (void*)&acc,
        (void*)&ticket, (void*)&out
    };
    hipLaunchCooperativeKernel(reinterpret_cast<void*>(k_fused),
                               dim3(NBLK), dim3(NTHR), kargs, 0, stream);
}

// Round 9
// 463.016 us; speedup vs baseline: 1.0668x; 1.0668x over previous
//
#include <hip/hip_runtime.h>
#include <hip/hip_cooperative_groups.h>
#include <math.h>

namespace cg = cooperative_groups;

#define BB 8
#define NCLS 16
#define NPIX 16384
#define CHN 256
#define MAXV 200
#define SORTN 2048
#define NC 8
#define NTHR 256
#define RBLK 512

typedef unsigned long long ull;

// ---------------- ws layout (bytes) ----------------
// 0       : double acc                 (zeroed by k_rest block 0 pre-sync)
// 8       : int ticket
// 64      : int gcnt[128]
// 1024    : float pos_sum[2048]
// 16384   : int counts_part[128*16]    (written fully by k_cert1)
// 65536   : ull thrKey[128]
// 1048576 : ull keybuf[128*2048]       (2 MB)
// 3145728 : float2 part[NC*8*16384]    (8 MB)

// dispatch 1 (standard launch, 1024 blocks): 8-deep float4 batched partial
// top-2 per (image, pixel-tile, channel-chunk); chunk-0 blocks histogram.
// This exact structure is the only Phase-A config measured fast (R5/R7).
__global__ __launch_bounds__(256) void k_cert1(const float* __restrict__ feats,
                                               const int* __restrict__ predict,
                                               float2* __restrict__ part,
                                               int* __restrict__ counts_part) {
    __shared__ int h[NCLS];
    int bid = blockIdx.x;                  // BB * 16 * NC = 1024 blocks
    int chunk = bid % NC;
    int tile  = (bid / NC) % 16;
    int b     = bid / (NC * 16);
    int tid = threadIdx.x;
    int n4 = tile * 1024 + tid * 4;
    bool do_hist = (chunk == 0);
    if (do_hist) {
        if (tid < NCLS) h[tid] = 0;
        __syncthreads();
        int4 pv = *(const int4*)(predict + b * NPIX + n4);
        int pvv[4] = {pv.x, pv.y, pv.z, pv.w};
#pragma unroll
        for (int q = 0; q < 4; ++q)
            if (pvv[q] >= 0 && pvv[q] < NCLS) atomicAdd(&h[pvv[q]], 1);
    }
    const float* fb = feats + (size_t)b * CHN * NPIX + n4;
    int c0 = chunk * (CHN / NC);
    float m1[4] = {-INFINITY, -INFINITY, -INFINITY, -INFINITY};
    float m2[4] = {-INFINITY, -INFINITY, -INFINITY, -INFINITY};
    for (int cb = c0; cb < c0 + CHN / NC; cb += 8) {
        float4 xs[8];
#pragma unroll
        for (int u = 0; u < 8; ++u)
            xs[u] = *(const float4*)(fb + (size_t)(cb + u) * NPIX);
#pragma unroll
        for (int u = 0; u < 8; ++u) {
            float xv[4] = {xs[u].x, xs[u].y, xs[u].z, xs[u].w};
#pragma unroll
            for (int q = 0; q < 4; ++q) {
                float val = xv[q];
                if (val > m1[q]) { m2[q] = m1[q]; m1[q] = val; }
                else if (val > m2[q]) m2[q] = val;
            }
        }
    }
    float2* po = part + (((size_t)(b * NC + chunk)) << 14) + n4;
#pragma unroll
    for (int q = 0; q < 4; ++q) po[q] = make_float2(m1[q], m2[q]);
    if (do_hist) {
        __syncthreads();
        if (tid < NCLS) counts_part[(b * 16 + tile) * NCLS + tid] = h[tid];
    }
}

// dispatch 2 (cooperative, 512 blocks x 256): everything else, 4 grid.syncs.
__global__ __launch_bounds__(NTHR, 2) void k_rest(
    const float2* __restrict__ part,
    const int* __restrict__ predict,
    const float* __restrict__ feats,
    const int* __restrict__ counts_part,
    ull* __restrict__ keybuf,
    ull* __restrict__ thrKey,
    int* __restrict__ gcnt,
    float* __restrict__ pos_sum,
    double* __restrict__ acc,
    int* __restrict__ ticket,
    float* __restrict__ out)
{
    cg::grid_group grid = cg::this_grid();
    __shared__ int pmap_l[128];
    __shared__ int pcls_l[128];
    __shared__ int Lp_l[128];
    __shared__ int chan_l[16];
    __shared__ int sP, sD, skv;
    __shared__ union {
        struct { int c[128]; int sc[128]; int mn[128]; int present[NCLS]; } b;
        struct { int lcount[NCLS]; int gbase[NCLS]; } c;
        struct { ull keys[SORTN]; int whist[4][256]; int scan[257]; int wtot[4];
                 ull sprefix; int sremain; int sdone; } d;
        float gacc[NCLS * 16];
        struct { float ppd[128 * 16]; float nr[128]; double red[NTHR]; } f;
    } su;

    const int tid  = threadIdx.x;
    const int bid  = blockIdx.x;
    const int lane = tid & 63;
    const int wv   = tid >> 6;
    const int t    = bid * NTHR + tid;       // global pixel id = b*NPIX + pix
    const int b    = t >> 14;                // block-uniform (256 px per block)
    const int pix  = t & (NPIX - 1);

    // ---- merge part -> certainty (register-resident; no cert buffer) ----
    float2 pm[NC];
#pragma unroll
    for (int j = 0; j < NC; ++j)
        pm[j] = part[(((size_t)(b * NC + j)) << 14) + pix];
    float m1 = -INFINITY, m2 = -INFINITY;
#pragma unroll
    for (int j = 0; j < NC; ++j) {
        if (pm[j].x > m1) { m2 = fmaxf(m1, pm[j].y); m1 = pm[j].x; }
        else              { m2 = fmaxf(m2, pm[j].x); }
    }
    const float ct = m1 - m2;
    const int v = predict[t];

    // ---- Phase B: plan, per-block in LDS; block 0 zeroes global accums ----
    if (bid == 0) {
        for (int i = tid; i < 2048; i += NTHR) pos_sum[i] = 0.f;
        if (tid < 128) gcnt[tid] = 0;
        if (tid == 0) { *acc = 0.0; *ticket = 0; }
    }
    if (tid < NCLS) su.b.present[tid] = 0;
    if (tid < 128) {
        int bb = tid >> 4, vv = tid & 15, s = 0;
        for (int t2 = 0; t2 < 16; ++t2) s += counts_part[((bb << 4) + t2) * NCLS + vv];
        su.b.c[tid] = s;
    }
    __syncthreads();
    int e = 0;
    if (tid < 128) {
        if (su.b.c[tid] > 0) atomicOr(&su.b.present[tid & 15], 1);
        e = (su.b.c[tid] >= MAXV) ? 1 : 0;
        su.b.sc[tid] = e;
        su.b.mn[tid] = e ? su.b.c[tid] : 0x7fffffff;
    }
    __syncthreads();
    for (int off = 1; off < 128; off <<= 1) {
        int add = 0;
        if (tid < 128 && tid >= off) add = su.b.sc[tid - off];
        __syncthreads();
        if (tid < 128) su.b.sc[tid] += add;
        __syncthreads();
    }
    for (int s2 = 64; s2 > 0; s2 >>= 1) {
        if (tid < s2) su.b.mn[tid] = min(su.b.mn[tid], su.b.mn[tid + s2]);
        __syncthreads();
    }
    if (tid < 128) {
        pmap_l[tid] = e ? (su.b.sc[tid] - 1) : -1;
        if (e) {
            int p2 = su.b.sc[tid] - 1;
            pcls_l[p2] = tid & 15;
            Lp_l[p2]   = su.b.c[tid];
        }
    }
    if (tid == 0) {
        int D = 0;
        for (int vv = 0; vv < NCLS; ++vv) if (su.b.present[vv]) chan_l[D++] = vv;
        sP  = su.b.sc[127];
        sD  = D;
        skv = su.b.mn[0] / 2;                // k = n_view // 2
    }
    __syncthreads();

    grid.sync();   // zeroed accumulators visible everywhere

    // ---- Phase C: block-aggregated two-pass key scatter (R7-proven) ----
    const int p = (v >= 0 && v < NCLS) ? pmap_l[(b << 4) + v] : -1;
    if (tid < NCLS) su.c.lcount[tid] = 0;
    __syncthreads();
    int lpos = 0;
    if (p >= 0) lpos = atomicAdd(&su.c.lcount[v], 1);
    __syncthreads();
    if (tid < NCLS) {
        int cc = su.c.lcount[tid];
        int pp = pmap_l[(b << 4) + tid];
        su.c.gbase[tid] = (pp >= 0 && cc > 0) ? atomicAdd(&gcnt[pp], cc) : 0;
    }
    __syncthreads();
    ull mykey = 0;
    if (p >= 0) {
        unsigned int mm = __float_as_uint(ct) | 0x80000000u;  // cert>=0 monotonic
        mykey = ((ull)mm << 32) | (ull)(0xFFFFFFFFu - (unsigned)pix);
        int pos = su.c.gbase[v] + lpos;
        if (pos < SORTN) keybuf[((size_t)p << 11) + pos] = mykey;
    }

    grid.sync();   // keybuf + gcnt visible

    // ---- Phase D: radix-select kv-th largest key (blocks 0..P-1) ----
    if (bid < sP) {
        const int p2 = bid;
        int L = gcnt[p2]; if (L > SORTN) L = SORTN;
        int kv = skv < L ? skv : L;
        if (tid == 0) { su.d.sprefix = 0; su.d.sremain = kv; su.d.sdone = 0; }
        for (int i = tid; i < L; i += NTHR) su.d.keys[i] = keybuf[((size_t)p2 << 11) + i];
        __syncthreads();
        for (int shift = 56; shift >= 0; shift -= 8) {
            if (su.d.sdone) break;                   // uniform (read post-barrier)
            for (int i = tid; i < 4 * 256; i += NTHR) ((int*)su.d.whist)[i] = 0;
            ull pref = su.d.sprefix;
            int rem  = su.d.sremain;
            __syncthreads();
            ull maskHi = (shift == 56) ? 0ULL : (~0ULL) << (shift + 8);
            for (int i = tid; i < L; i += NTHR) {
                ull kk = su.d.keys[i];
                if ((kk & maskHi) == pref)
                    atomicAdd(&su.d.whist[wv][(int)((kk >> shift) & 255)], 1);
            }
            __syncthreads();
            int s = su.d.whist[0][tid] + su.d.whist[1][tid]
                  + su.d.whist[2][tid] + su.d.whist[3][tid];
            for (int off = 1; off < 64; off <<= 1) {      // wave suffix scan
                int o = __shfl_down(s, off, 64);
                if (lane + off < 64) s += o;
            }
            if (lane == 0) su.d.wtot[wv] = s;
            __syncthreads();
            {
                int offs = 0;
                for (int w2 = wv + 1; w2 < 4; ++w2) offs += su.d.wtot[w2];
                s += offs;
                su.d.scan[tid] = s;
                if (tid == 0) su.d.scan[256] = 0;
            }
            __syncthreads();
            {
                int nxt = su.d.scan[tid + 1];
                if (s >= rem && nxt < rem) {              // crossing bin
                    su.d.sprefix = pref | ((ull)tid << shift);
                    su.d.sremain = rem - nxt;
                    if (s == rem) su.d.sdone = 1;         // low bits irrelevant
                }
            }
            __syncthreads();
        }
        if (tid == 0) thrKey[p2] = su.d.sprefix;
    }

    grid.sync();   // thrKey visible

    // ---- Phase E: re-read 16 loss channels (coalesced, L3-warm) + accum ----
    const int D = sD;
    const bool ident = (D == 16);     // classes ⊂ [0,16) sorted ⇒ chan = identity
    const float* fp = feats + ((size_t)b * CHN << 14) + pix;
    float x16[16];
    if (ident) {
#pragma unroll
        for (int d2 = 0; d2 < 16; ++d2) x16[d2] = fp[(size_t)d2 << 14];
    } else {
        for (int d2 = 0; d2 < D; ++d2) x16[d2] = fp[(size_t)chan_l[d2] << 14];
    }
    bool selp = (p >= 0) && (mykey >= thrKey[p]);
    su.gacc[tid] = 0.f;
    __syncthreads();
    if (selp) {
        if (ident) {
#pragma unroll
            for (int d2 = 0; d2 < 16; ++d2) atomicAdd(&su.gacc[(v << 4) + d2], x16[d2]);
        } else {
            for (int d2 = 0; d2 < D; ++d2) atomicAdd(&su.gacc[(v << 4) + d2], x16[d2]);
        }
    }
    __syncthreads();
    {
        int pp = pmap_l[(b << 4) + (tid >> 4)];
        if (pp >= 0 && su.gacc[tid] != 0.f)
            atomicAdd(&pos_sum[(pp << 4) + (tid & 15)], su.gacc[tid]);
    }

    grid.sync();   // pos_sum complete

    // ---- Phase F: inter loss (all), intra pair loss (block 0), publish ----
    const int P = sP;
    for (int i = tid; i < (P << 4); i += NTHR) su.f.ppd[i] = pos_sum[i];
    __syncthreads();
    for (int pp = tid; pp < P; pp += NTHR) {
        float s = 0.f;
#pragma unroll
        for (int d2 = 0; d2 < 16; ++d2) { float y = su.f.ppd[(pp << 4) + d2]; s += y * y; }
        su.f.nr[pp] = sqrtf(s);
    }
    __syncthreads();
    double term = 0.0;
    if (p >= 0) {
        float dot = 0.f, nv2 = 0.f;
        if (ident) {
#pragma unroll
            for (int d2 = 0; d2 < 16; ++d2) {
                float y = su.f.ppd[(p << 4) + d2];
                dot += x16[d2] * y; nv2 += x16[d2] * x16[d2];
            }
        } else {
            for (int d2 = 0; d2 < D; ++d2) {
                float y = su.f.ppd[(p << 4) + d2];
                dot += x16[d2] * y; nv2 += x16[d2] * x16[d2];
            }
        }
        float den = fmaxf(sqrtf(nv2) * su.f.nr[p], 1e-8f);
        term = (1.0 - (double)(dot / den)) / ((double)Lp_l[p] * (double)P);
    }
    su.f.red[tid] = term;
    __syncthreads();
    for (int s2 = 128; s2 > 0; s2 >>= 1) {
        if (tid < s2) su.f.red[tid] += su.f.red[tid + s2];
        __syncthreads();
    }
    if (tid == 0) atomicAdd(acc, su.f.red[0]);

    if (bid == 0) {
        __syncthreads();
        double num = 0.0; int cnt = 0;
        for (int idx = tid; idx < P * P; idx += NTHR) {
            int i2 = idx / P, j2 = idx - i2 * P;
            if (pcls_l[i2] != pcls_l[j2]) {
                float dot = 0.f;
#pragma unroll
                for (int d2 = 0; d2 < 16; ++d2)
                    dot += su.f.ppd[(i2 << 4) + d2] * su.f.ppd[(j2 << 4) + d2];
                num += (double)(dot / (su.f.nr[i2] * su.f.nr[j2])) + 1.0;
                cnt++;
            }
        }
        su.f.red[tid] = num; __syncthreads();
        for (int s2 = 128; s2 > 0; s2 >>= 1) {
            if (tid < s2) su.f.red[tid] += su.f.red[tid + s2];
            __syncthreads();
        }
        double totnum = su.f.red[0]; __syncthreads();
        su.f.red[tid] = (double)cnt; __syncthreads();
        for (int s2 = 128; s2 > 0; s2 >>= 1) {
            if (tid < s2) su.f.red[tid] += su.f.red[tid + s2];
            __syncthreads();
        }
        if (tid == 0) atomicAdd(acc, totnum / su.f.red[0]);
    }
    __syncthreads();
    __threadfence();
    if (tid == 0) {
        int done = atomicAdd(ticket, 1);
        if (done == (int)gridDim.x - 1)
            out[0] = (float)atomicAdd(acc, 0.0);   // coherent read of final sum
    }
}

extern "C" void kernel_launch(void* const* d_in, const int* in_sizes, int n_in,
                              void* d_out, int out_size, void* d_ws, size_t ws_size,
                              hipStream_t stream) {
    (void)in_sizes; (void)n_in; (void)out_size; (void)ws_size;
    const float* feats = (const float*)d_in[0];
    const int* predict = (const int*)d_in[2];   // labels (d_in[1]) unused
    char* ws = (char*)d_ws;
    double* acc      = (double*)ws;
    int* ticket      = (int*)(ws + 8);
    int* gcnt        = (int*)(ws + 64);
    float* pos_sum   = (float*)(ws + 1024);
    int* counts_part = (int*)(ws + 16384);
    ull* thrKey      = (ull*)(ws + 65536);
    ull* keybuf      = (ull*)(ws + 1048576);
    float2* part     = (float2*)(ws + 3145728);
    float* out       = (float*)d_out;

    k_cert1<<<BB * 16 * NC, 256, 0, stream>>>(feats, predict, part, counts_part);

    const float2* partc = part;
    void* kargs[] = {
        (void*)&partc, (void*)&predict, (void*)&feats, (void*)&counts_part,
        (void*)&keybuf, (void*)&thrKey, (void*)&gcnt, (void*)&pos_sum,
        (void*)&acc, (void*)&ticket, (void*)&out
    };
    hipLaunchCooperativeKernel(reinterpret_cast<void*>(k_rest),
                               dim3(RBLK), dim3(NTHR), kargs, 0, stream);
}